// Round 1
// baseline (67.658 us; speedup 1.0000x reference)
//
#include <hip/hip_runtime.h>
#include <hip/hip_bf16.h>
#include <stdint.h>

#define NB   16
#define CIN  2048
#define OUTC 256
#define HW   1024
#define BJ   64
#define BK   32
#define NJT  (HW / BJ)          // 16 j-tiles
#define KSTEPS (CIN / BK)       // 64
#define APAD 40                 // padded LDS row length in bf16 (32 payload + 8 pad; 80 B = 16B-aligned)

typedef __attribute__((ext_vector_type(8))) short bf16x8;
typedef __attribute__((ext_vector_type(4))) float f32x4;
typedef __attribute__((ext_vector_type(4))) unsigned int u32x4;

__device__ __forceinline__ unsigned int f2bf(float f) {
    union { float f; unsigned int u; } a; a.f = f;
    return (a.u + 0x7FFFu + ((a.u >> 16) & 1u)) >> 16;  // RNE
}

// ---- kernel 1: W fp32 -> bf16 (1 MiB, L2-resident for the GEMM) ----
__global__ void wconv_kernel(const float* __restrict__ W, unsigned short* __restrict__ W16) {
    int i = (blockIdx.x * blockDim.x + threadIdx.x) * 4;
    float4 v = *reinterpret_cast<const float4*>(W + i);
    ushort4 o;
    o.x = (unsigned short)f2bf(v.x);
    o.y = (unsigned short)f2bf(v.y);
    o.z = (unsigned short)f2bf(v.z);
    o.w = (unsigned short)f2bf(v.w);
    *reinterpret_cast<ushort4*>(W16 + i) = o;
}

// ---- kernel 2: per-batch GEMM y = W x_n with in-register reduction to
//      s1_part[jt][n][o] (spatial partial sums) and s2_part[blk][o] (sum of squares).
//      BM=256 (full channel dim -> each x element read exactly once), BN=64, BK=32.
__global__ __launch_bounds__(512, 1) void gemm_stats_kernel(
    const float* __restrict__ x,             // [16][2048][1024]
    const unsigned short* __restrict__ W16,  // [256][2048] bf16
    float* __restrict__ s1_part,             // [NJT][NB][OUTC]
    float* __restrict__ s2_part)             // [NB*NJT][OUTC]
{
    __shared__ __align__(16) unsigned short Asm[256][APAD]; // [o][k], 20 KB
    __shared__ __align__(16) unsigned short Bsm[BJ][APAD];  // [j][k] (transposed), 5 KB

    const int tid  = threadIdx.x;
    const int lane = tid & 63;
    const int wave = tid >> 6;     // 0..7, wave's rows = [32w, 32w+32)
    const int blk  = blockIdx.x;   // 0..255
    const int n    = blk >> 4;
    const int jt   = blk & 15;
    const int j0   = jt * BJ;

    const float* xn = x + (size_t)n * CIN * HW;

    // A staging: thread -> (row = tid>>1, half = tid&1): 16 bf16 = 2x 16B loads
    const int arow  = tid >> 1;
    const int ahalf = tid & 1;
    const unsigned short* Ag = W16 + arow * CIN + ahalf * 16;

    // B staging: thread -> (j = tid&63, q = tid>>6): 4 floats (c = q*4+i), coalesced
    const int bj = tid & 63;
    const int bq = tid >> 6;
    const float* Bg = xn + (size_t)(bq * 4) * HW + j0 + bj;

    // prefetch K-step 0 into registers
    u32x4 a0 = *(const u32x4*)(Ag);
    u32x4 a1 = *(const u32x4*)(Ag + 8);
    float b0 = Bg[0], b1 = Bg[HW], b2 = Bg[2 * HW], b3 = Bg[3 * HW];

    f32x4 acc[2][4] = {};

    const int rA   = lane & 15;   // fragment row/col index
    const int gK   = lane >> 4;   // k-group: k = gK*8 + i
    const int aoff = gK * 8;

    for (int ks = 0; ks < KSTEPS; ++ks) {
        __syncthreads();                       // prev step's LDS reads complete
        *(u32x4*)&Asm[arow][ahalf * 16]     = a0;
        *(u32x4*)&Asm[arow][ahalf * 16 + 8] = a1;
        unsigned int p0 = f2bf(b0) | (f2bf(b1) << 16);
        unsigned int p1 = f2bf(b2) | (f2bf(b3) << 16);
        *(uint2*)&Bsm[bj][bq * 4] = make_uint2(p0, p1);
        if (ks + 1 < KSTEPS) {                 // issue next step's loads; fly during MFMA
            const unsigned short* Ag2 = Ag + (ks + 1) * BK;
            a0 = *(const u32x4*)(Ag2);
            a1 = *(const u32x4*)(Ag2 + 8);
            const float* Bg2 = Bg + (size_t)(ks + 1) * BK * HW;
            b0 = Bg2[0]; b1 = Bg2[HW]; b2 = Bg2[2 * HW]; b3 = Bg2[3 * HW];
        }
        __syncthreads();                       // staged data visible

        bf16x8 af0 = *(const bf16x8*)&Asm[wave * 32 + rA][aoff];
        bf16x8 af1 = *(const bf16x8*)&Asm[wave * 32 + 16 + rA][aoff];
        bf16x8 bfr[4];
        #pragma unroll
        for (int ni = 0; ni < 4; ++ni)
            bfr[ni] = *(const bf16x8*)&Bsm[ni * 16 + rA][aoff];
        #pragma unroll
        for (int ni = 0; ni < 4; ++ni) {
            acc[0][ni] = __builtin_amdgcn_mfma_f32_16x16x32_bf16(af0, bfr[ni], acc[0][ni], 0, 0, 0);
            acc[1][ni] = __builtin_amdgcn_mfma_f32_16x16x32_bf16(af1, bfr[ni], acc[1][ni], 0, 0, 0);
        }
    }

    // ---- epilogue: per-row (channel o) sum and sum-of-squares over this block's 64 j ----
    // C/D layout: col(j) = lane&15, row = (lane>>4)*4 + r  [m89]
    float rs[2][4], rq[2][4];
    #pragma unroll
    for (int mi = 0; mi < 2; ++mi) {
        #pragma unroll
        for (int r = 0; r < 4; ++r) {
            float s = 0.f, q = 0.f;
            #pragma unroll
            for (int ni = 0; ni < 4; ++ni) {
                float v = acc[mi][ni][r];
                s += v; q += v * v;
            }
            rs[mi][r] = s; rq[mi][r] = q;
        }
    }
    #pragma unroll
    for (int m = 1; m < 16; m <<= 1) {         // reduce across the 16 j-lanes
        #pragma unroll
        for (int mi = 0; mi < 2; ++mi) {
            #pragma unroll
            for (int r = 0; r < 4; ++r) {
                rs[mi][r] += __shfl_xor(rs[mi][r], m, 64);
                rq[mi][r] += __shfl_xor(rq[mi][r], m, 64);
            }
        }
    }
    if (rA == 0) {
        #pragma unroll
        for (int mi = 0; mi < 2; ++mi) {
            #pragma unroll
            for (int r = 0; r < 4; ++r) {
                int o = wave * 32 + mi * 16 + gK * 4 + r;
                s1_part[(jt * NB + n) * OUTC + o] = rs[mi][r];
                s2_part[blk * OUTC + o]           = rq[mi][r];
            }
        }
    }
}

// ---- kernel 3: reduce partials -> BN stats -> pooled[n][o] (deterministic) ----
__global__ void finalize_kernel(const float* __restrict__ s1_part,
                                const float* __restrict__ s2_part,
                                const float* __restrict__ gamma,
                                const float* __restrict__ beta,
                                float* __restrict__ pooled) {
    int o = threadIdx.x;  // 256
    float S2 = 0.f;
    for (int b = 0; b < NB * NJT; ++b) S2 += s2_part[b * OUTC + o];
    float s1n[NB];
    float S1 = 0.f;
    #pragma unroll
    for (int n = 0; n < NB; ++n) {
        float s = 0.f;
        #pragma unroll
        for (int t = 0; t < NJT; ++t) s += s1_part[(t * NB + n) * OUTC + o];
        s1n[n] = s; S1 += s;
    }
    float mean = S1 * (1.f / 16384.f);
    float var  = S2 * (1.f / 16384.f) - mean * mean;   // biased var, matches ref
    float inv  = rsqrtf(var + 1e-5f);
    float g = gamma[o], b = beta[o];
    #pragma unroll
    for (int n = 0; n < NB; ++n)
        pooled[n * OUTC + o] = g * (s1n[n] * (1.f / 1024.f) - mean) * inv + b;
}

// ---- kernel 4: broadcast pooled to [NB][OUTC][32][32] ----
__global__ void bcast_kernel(const float* __restrict__ pooled, float* __restrict__ out) {
    int p = blockIdx.x;                 // n*256 + o
    float v = pooled[p];
    float4 vv = make_float4(v, v, v, v);
    reinterpret_cast<float4*>(out + (size_t)p * HW)[threadIdx.x] = vv;
}

extern "C" void kernel_launch(void* const* d_in, const int* in_sizes, int n_in,
                              void* d_out, int out_size, void* d_ws, size_t ws_size,
                              hipStream_t stream) {
    const float* x     = (const float*)d_in[0];
    const float* W     = (const float*)d_in[1];
    const float* gamma = (const float*)d_in[2];
    const float* beta  = (const float*)d_in[3];
    float* out = (float*)d_out;

    char* ws = (char*)d_ws;
    unsigned short* W16 = (unsigned short*)ws;                   // 1 MiB
    float* s1_part = (float*)(ws + (1 << 20));                   // 256 KB
    float* s2_part = (float*)(ws + (1 << 20) + (256 << 10));     // 256 KB
    float* pooled  = (float*)(ws + (1 << 20) + (512 << 10));     // 16 KB

    hipLaunchKernelGGL(wconv_kernel, dim3(512), dim3(256), 0, stream, W, W16);
    hipLaunchKernelGGL(gemm_stats_kernel, dim3(256), dim3(512), 0, stream,
                       x, W16, s1_part, s2_part);
    hipLaunchKernelGGL(finalize_kernel, dim3(1), dim3(OUTC), 0, stream,
                       s1_part, s2_part, gamma, beta, pooled);
    hipLaunchKernelGGL(bcast_kernel, dim3(NB * OUTC), dim3(256), 0, stream, pooled, out);
}